// Round 4
// baseline (139.185 us; speedup 1.0000x reference)
//
#include <hip/hip_runtime.h>

#define HH 128
#define WW 128
#define CC 64
#define CO 64
#define BB 4
#define GG 8
#define CG 8
#define KK 9
#define HW (HH*WW)

typedef __attribute__((ext_vector_type(8))) short short8;
typedef __attribute__((ext_vector_type(4))) float floatx4;
typedef __attribute__((ext_vector_type(2))) float f32x2;

union S8I { short8 s; int i[4]; };
union FU { float f; unsigned u; };

__device__ inline short f2bf(float f) {
    FU v; v.f = f;
    return (short)((v.u + 0x7FFF + ((v.u >> 16) & 1)) >> 16);
}
__device__ inline unsigned rnd2(float f) {   // round-half-up bf16 in bits [31:16]
    FU v; v.f = f;
    return v.u + 0x8000u;
}
__device__ inline float bflo(int e) { union { int i; float f; } u; u.i = e << 16; return u.f; }
__device__ inline float bfhi(int e) { union { int i; float f; } u; u.i = e & 0xffff0000; return u.f; }

// ---- merged prep (unchanged) ----
// A-frag layout for the half-K GEMM: fid = (h*9+gc)*4 + ot,
//   wf[fid*512 + L*8 + j] = bf16(W[o=ot*16+(L&15)][g=h*4+(L>>4)][cg=j][kk=gc])
// Input NCHW f32 -> in_t[b][g][y*W+x][cg] bf16 (16B per pixel-group).
__global__ __launch_bounds__(256)
void prep(const float* __restrict__ wt, const float* __restrict__ in,
          short* __restrict__ wf, short* __restrict__ in_t) {
    const int bid = blockIdx.x;
    if (bid < 144) {
        const int tid = bid * 256 + threadIdx.x;   // < 36864 = 576*64
        const int j   = tid & 7;
        const int L   = (tid >> 3) & 63;
        const int fid = tid >> 9;                  // (h*9+gc)*4 + ot, 0..71
        const int ot  = fid & 3;
        const int gch = fid >> 2;                  // h*9 + gc, 0..17
        const int h   = gch / 9, gc = gch - h * 9;
        const int o   = ot * 16 + (L & 15);
        const int g   = h * 4 + (L >> 4);
        wf[tid] = f2bf(wt[o * 576 + (g * 8 + j) * 9 + gc]);
    } else {
        const int idx = bid - 144;                 // 2048 blocks: 64 x 8 x 4
        const int bx = idx & 63;
        const int g  = (idx >> 6) & 7;
        const int b  = idx >> 9;
        const int p  = bx * 256 + threadIdx.x;
        const float* src = in + (b * CC + g * CG) * HW + p;
        short8 v;
        #pragma unroll
        for (int cg = 0; cg < CG; ++cg) v[cg] = f2bf(src[cg * HW]);
        *(short8*)(in_t + ((b * GG + g) * HW + p) * 8) = v;
    }
}

// v3: B-frag-direct, batched gathers, OCCUPANCY-FIRST.
// Round-3 lesson: 72KB s_wf at 256-thr blocks -> 8 waves/CU (occ 19.5%) and
// latency-bound time tracks wave count. Fix: 512-thr blocks (8 waves, full
// 128-px row) amortize the same 72KB over 2x the waves -> 16 waves/CU cap,
// equal to round-0 but with ZERO inner barriers. __launch_bounds__(512,4)
// caps VGPR at 128; gather batches of 3 taps (48 VGPR) keep us under it.
__global__ __launch_bounds__(512, 4)
void dcn_fused(const short* __restrict__ in_t, const float* __restrict__ off,
               const float* __restrict__ msk, const short* __restrict__ wf,
               const float* __restrict__ bias, float* __restrict__ out)
{
    __shared__ short s_wf[72 * 512];   // 73728 B: all A-fragments

    const int t  = threadIdx.x;
    // one-shot cooperative copy, 16B/lane contiguous (coalesced, conflict-free)
    #pragma unroll
    for (int k = 0; k < 9; ++k) {
        const int idx = (k * 512 + t) * 8;
        *(short8*)(s_wf + idx) = *(const short8*)(wf + idx);
    }
    __syncthreads();   // only barrier in the kernel

    // bijective XCD swizzle: 512 % 8 == 0 -> each XCD gets 64 contiguous rows
    const int lin = (blockIdx.x & 7) * 64 + (blockIdx.x >> 3);
    const int b   = lin >> 7;          // 0..3
    const int ho  = lin & 127;         // 0..127

    const int w = t >> 6, lane = t & 63;       // w = 0..7: px strip
    const int q4 = lane >> 4, n16 = lane & 15;
    const int px = w * 16 + n16;               // this lane's output pixel
    const int basepix = ho * WW + px;

    floatx4 acc[4];
    #pragma unroll
    for (int ot = 0; ot < 4; ++ot)
        #pragma unroll
        for (int r = 0; r < 4; ++r)
            acc[ot][r] = bias[ot * 16 + q4 * 4 + r];

    const char* ib = (const char*)(in_t + (long)b * GG * HW * 8);

    #pragma unroll
    for (int h = 0; h < 2; ++h) {
        const int g = h * 4 + q4;      // per-LANE offset group (B-frag k-block)

        // ---- preload off/mask: 27 independent loads ----
        float pdy[9], pdx[9], pm[9];
        #pragma unroll
        for (int i = 0; i < 9; ++i) {
            const int offc = (b * 144 + g * 18 + i * 2) * HW + basepix;
            pdy[i] = off[offc];
            pdx[i] = off[offc + HW];
            pm[i]  = msk[(b * 72 + g * 9 + i) * HW + basepix];
        }

        const int gsh = g << 18;

        // 3 batches x 3 taps: issue 12 corner loads, then consume tap-by-tap
        // (in-order vmcnt: tap j's consume waits only for loads <= its own).
        S8I u00[3], u01[3], u10[3], u11[3];   // static-indexed -> VGPRs
        float cw00[3], cw01[3], cw10[3], cw11[3];

        #pragma unroll
        for (int batch = 0; batch < 3; ++batch) {
            const int i0 = batch * 3;

            // ---- issue: addresses + weights + corner loads for 3 taps ----
            #pragma unroll
            for (int j = 0; j < 3; ++j) {
                const int i = i0 + j;
                const int ky = i / 3, kx = i - (i / 3) * 3;   // consts

                const float py  = (float)(ho - 1 + ky) + pdy[i];
                const float pxf = (float)(px - 1 + kx) + pdx[i];
                const float y0f = floorf(py), x0f = floorf(pxf);
                const float ly = py - y0f, lx = pxf - x0f;
                const int y0 = (int)y0f, x0 = (int)x0f;
                const int y1 = y0 + 1,  x1 = x0 + 1;

                const float vy0 = (y0 >= 0 && y0 < HH) ? 1.f : 0.f;
                const float vy1 = (y1 >= 0 && y1 < HH) ? 1.f : 0.f;
                const float vx0 = (x0 >= 0 && x0 < WW) ? 1.f : 0.f;
                const float vx1 = (x1 >= 0 && x1 < WW) ? 1.f : 0.f;
                const int y0c = min(max(y0, 0), HH - 1), y1c = min(max(y1, 0), HH - 1);
                const int x0c = min(max(x0, 0), WW - 1), x1c = min(max(x1, 0), WW - 1);

                const float m = pm[i];
                const float wy0 = (1.f - ly) * vy0 * m;
                const float wy1 = ly * vy1 * m;
                const float wx0 = (1.f - lx) * vx0;
                const float wx1 = lx * vx1;
                cw00[j] = wy0 * wx0; cw01[j] = wy0 * wx1;
                cw10[j] = wy1 * wx0; cw11[j] = wy1 * wx1;

                const int y0sh = gsh + (y0c << 11), y1sh = gsh + (y1c << 11);
                const int x0sh = x0c << 4, x1sh = x1c << 4;
                u00[j].s = *(const short8*)(ib + (y0sh + x0sh));
                u01[j].s = *(const short8*)(ib + (y0sh + x1sh));
                u10[j].s = *(const short8*)(ib + (y1sh + x0sh));
                u11[j].s = *(const short8*)(ib + (y1sh + x1sh));
            }

            // ---- consume: interp + MFMA; A-frags from LDS (lgkmcnt) ----
            #pragma unroll
            for (int j = 0; j < 3; ++j) {
                const int i = i0 + j;
                const f32x2 W00 = {cw00[j], cw00[j]}, W01 = {cw01[j], cw01[j]};
                const f32x2 W10 = {cw10[j], cw10[j]}, W11 = {cw11[j], cw11[j]};
                S8I res;
                #pragma unroll
                for (int pc = 0; pc < 4; ++pc) {
                    const int e00 = u00[j].i[pc], e01 = u01[j].i[pc];
                    const int e10 = u10[j].i[pc], e11 = u11[j].i[pc];
                    f32x2 a00 = {bflo(e00), bfhi(e00)};
                    f32x2 a01 = {bflo(e01), bfhi(e01)};
                    f32x2 a10 = {bflo(e10), bfhi(e10)};
                    f32x2 a11 = {bflo(e11), bfhi(e11)};
                    f32x2 v = a00 * W00;
                    v += a01 * W01;
                    v += a10 * W10;
                    v += a11 * W11;
                    res.i[pc] = (int)__builtin_amdgcn_perm(rnd2(v.y), rnd2(v.x), 0x07060302u);
                }

                // res.s IS the B-fragment for chunk (h,i)
                #pragma unroll
                for (int ot = 0; ot < 4; ++ot) {
                    const short8 afr = *(const short8*)&s_wf[((h * 9 + i) * 4 + ot) * 512 + lane * 8];
                    acc[ot] = __builtin_amdgcn_mfma_f32_16x16x32_bf16(afr, res.s, acc[ot], 0, 0, 0);
                }
            }
        }
    }

    // ---- epilogue: o = ot*16 + q4*4 + r ----
    #pragma unroll
    for (int ot = 0; ot < 4; ++ot)
        #pragma unroll
        for (int r = 0; r < 4; ++r)
            out[((b * CO + ot * 16 + q4 * 4 + r) * HH + ho) * WW + px] = acc[ot][r];
}

extern "C" void kernel_launch(void* const* d_in, const int* in_sizes, int n_in,
                              void* d_out, int out_size, void* d_ws, size_t ws_size,
                              hipStream_t stream) {
    const float* in   = (const float*)d_in[0];
    const float* off  = (const float*)d_in[1];
    const float* msk  = (const float*)d_in[2];
    const float* wt   = (const float*)d_in[3];
    const float* bias = (const float*)d_in[4];
    float* out = (float*)d_out;
    short* wf   = (short*)d_ws;            // 36864 shorts = 72 KB
    short* in_t = (short*)d_ws + 36864;    // 4*8*16384*8 shorts = 8 MB

    prep<<<144 + 2048, 256, 0, stream>>>(wt, in, wf, in_t);

    dcn_fused<<<512, 512, 0, stream>>>(in_t, off, msk, wf, bias, out);
}

// Round 5
// 134.975 us; speedup vs baseline: 1.0312x; 1.0312x over previous
//
#include <hip/hip_runtime.h>

#define HH 128
#define WW 128
#define CC 64
#define CO 64
#define BB 4
#define GG 8
#define CG 8
#define KK 9
#define HW (HH*WW)

typedef __attribute__((ext_vector_type(8))) short short8;
typedef __attribute__((ext_vector_type(4))) float floatx4;
typedef __attribute__((ext_vector_type(2))) float f32x2;

union S8I { short8 s; int i[4]; };
union FU { float f; unsigned u; };

__device__ inline short f2bf(float f) {
    FU v; v.f = f;
    return (short)((v.u + 0x7FFF + ((v.u >> 16) & 1)) >> 16);
}
__device__ inline unsigned rnd2(float f) {   // round-half-up bf16 in bits [31:16]
    FU v; v.f = f;
    return v.u + 0x8000u;
}
__device__ inline float bflo(int e) { union { int i; float f; } u; u.i = e << 16; return u.f; }
__device__ inline float bfhi(int e) { union { int i; float f; } u; u.i = e & 0xffff0000; return u.f; }

// ---- merged prep (unchanged) ----
// A-frag layout for the half-K GEMM: fid = (h*9+gc)*4 + ot,
//   wf[fid*512 + L*8 + j] = bf16(W[o=ot*16+(L&15)][g=h*4+(L>>4)][cg=j][kk=gc])
// Input NCHW f32 -> in_t[b][g][y*W+x][cg] bf16 (16B per pixel-group).
__global__ __launch_bounds__(256)
void prep(const float* __restrict__ wt, const float* __restrict__ in,
          short* __restrict__ wf, short* __restrict__ in_t) {
    const int bid = blockIdx.x;
    if (bid < 144) {
        const int tid = bid * 256 + threadIdx.x;   // < 36864 = 576*64
        const int j   = tid & 7;
        const int L   = (tid >> 3) & 63;
        const int fid = tid >> 9;                  // (h*9+gc)*4 + ot, 0..71
        const int ot  = fid & 3;
        const int gch = fid >> 2;                  // h*9 + gc, 0..17
        const int h   = gch / 9, gc = gch - h * 9;
        const int o   = ot * 16 + (L & 15);
        const int g   = h * 4 + (L >> 4);
        wf[tid] = f2bf(wt[o * 576 + (g * 8 + j) * 9 + gc]);
    } else {
        const int idx = bid - 144;                 // 2048 blocks: 64 x 8 x 4
        const int bx = idx & 63;
        const int g  = (idx >> 6) & 7;
        const int b  = idx >> 9;
        const int p  = bx * 256 + threadIdx.x;
        const float* src = in + (b * CC + g * CG) * HW + p;
        short8 v;
        #pragma unroll
        for (int cg = 0; cg < CG; ++cg) v[cg] = f2bf(src[cg * HW]);
        *(short8*)(in_t + ((b * GG + g) * HW + p) * 8) = v;
    }
}

// v4: B-frag-direct + per-half LDS A-frags + sched_barrier-fenced gather batches.
// Lessons so far:
//  r1: A-frag global loads inside taps poison the in-order vmcnt stream -> 63us.
//  r3/r4: 72KB s_wf halves occupancy (19-25%) -> 62/48us; compiler sinks
//         register gather batches 3x in a row (VGPR 56-88).
//  r0 (44us, best): barrier-phased gather pipeline at low reg pressure.
// This kernel: stage only the CURRENT half's A-frags (36.9KB -> 4 blocks/CU,
// 16-wave cap like r0); afr reads are lgkmcnt (never drain gathers); gathers
// issue in 3-tap batches behind __builtin_amdgcn_sched_barrier(0) so the
// scheduler CANNOT sink them; MFMA per tap is now harmless. 3 barriers total.
__global__ __launch_bounds__(256, 4)
void dcn_fused(const short* __restrict__ in_t, const float* __restrict__ off,
               const float* __restrict__ msk, const short* __restrict__ wf,
               const float* __restrict__ bias, float* __restrict__ out)
{
    __shared__ short s_wf[36 * 512];   // 36,864 B: ONE half's A-fragments

    const int t = threadIdx.x;

    // bijective XCD swizzle over 1024 blocks (1024 % 8 == 0)
    const int lin = (blockIdx.x & 7) * 128 + (blockIdx.x >> 3);
    const int b   = lin >> 8;          // 0..3
    const int rem = lin & 255;
    const int ho  = rem >> 1;          // 0..127
    const int bx  = rem & 1;           // 0..1

    const int w = t >> 6, lane = t & 63;
    const int q4 = lane >> 4, n16 = lane & 15;
    const int px = bx * 64 + w * 16 + n16;    // this lane's output pixel
    const int basepix = ho * WW + px;

    floatx4 acc[4];
    #pragma unroll
    for (int ot = 0; ot < 4; ++ot)
        #pragma unroll
        for (int r = 0; r < 4; ++r)
            acc[ot][r] = bias[ot * 16 + q4 * 4 + r];

    const char* ib = (const char*)(in_t + (long)b * GG * HW * 8);

    #pragma unroll
    for (int h = 0; h < 2; ++h) {
        // ---- stage this half's 36 A-frags into LDS (144 B/thread) ----
        if (h) __syncthreads();            // all waves done reading half 0
        #pragma unroll
        for (int k = 0; k < 9; ++k) {
            const int idx = (k * 256 + t) * 8;
            *(short8*)(s_wf + idx) = *(const short8*)(wf + h * 18432 + idx);
        }
        __syncthreads();

        const int g = h * 4 + q4;      // per-LANE offset group (B-frag k-block)

        // ---- preload off/mask: 27 independent coalesced loads ----
        float pdy[9], pdx[9], pm[9];
        #pragma unroll
        for (int i = 0; i < 9; ++i) {
            const int offc = (b * 144 + g * 18 + i * 2) * HW + basepix;
            pdy[i] = off[offc];
            pdx[i] = off[offc + HW];
            pm[i]  = msk[(b * 72 + g * 9 + i) * HW + basepix];
        }

        const int gsh = g << 18;

        // ---- 3 fenced batches of 3 taps ----
        #pragma unroll
        for (int q = 0; q < 3; ++q) {
            const int i0 = q * 3;
            S8I u00[3], u01[3], u10[3], u11[3];     // static-indexed -> VGPRs
            float cw00[3], cw01[3], cw10[3], cw11[3];

            // issue: weights + 12 corner loads
            #pragma unroll
            for (int j = 0; j < 3; ++j) {
                const int i = i0 + j;
                const int ky = i / 3, kx = i - (i / 3) * 3;   // consts

                const float py  = (float)(ho - 1 + ky) + pdy[i];
                const float pxf = (float)(px - 1 + kx) + pdx[i];
                const float y0f = floorf(py), x0f = floorf(pxf);
                const float ly = py - y0f, lx = pxf - x0f;
                const int y0 = (int)y0f, x0 = (int)x0f;
                const int y1 = y0 + 1,  x1 = x0 + 1;

                const float vy0 = (y0 >= 0 && y0 < HH) ? 1.f : 0.f;
                const float vy1 = (y1 >= 0 && y1 < HH) ? 1.f : 0.f;
                const float vx0 = (x0 >= 0 && x0 < WW) ? 1.f : 0.f;
                const float vx1 = (x1 >= 0 && x1 < WW) ? 1.f : 0.f;
                const int y0c = min(max(y0, 0), HH - 1), y1c = min(max(y1, 0), HH - 1);
                const int x0c = min(max(x0, 0), WW - 1), x1c = min(max(x1, 0), WW - 1);

                const float m = pm[i];
                const float wy0 = (1.f - ly) * vy0 * m;
                const float wy1 = ly * vy1 * m;
                const float wx0 = (1.f - lx) * vx0;
                const float wx1 = lx * vx1;
                cw00[j] = wy0 * wx0; cw01[j] = wy0 * wx1;
                cw10[j] = wy1 * wx0; cw11[j] = wy1 * wx1;

                const int y0sh = gsh + (y0c << 11), y1sh = gsh + (y1c << 11);
                const int x0sh = x0c << 4, x1sh = x1c << 4;
                u00[j].s = *(const short8*)(ib + (y0sh + x0sh));
                u01[j].s = *(const short8*)(ib + (y0sh + x1sh));
                u10[j].s = *(const short8*)(ib + (y1sh + x0sh));
                u11[j].s = *(const short8*)(ib + (y1sh + x1sh));
            }

            // fence: nothing (esp. the 12 loads above) may be sunk past here
            __builtin_amdgcn_sched_barrier(0);

            // consume: interp + 4x(ds_read afr + MFMA) per tap; counted vmcnt
            #pragma unroll
            for (int j = 0; j < 3; ++j) {
                const int i = i0 + j;
                const f32x2 W00 = {cw00[j], cw00[j]}, W01 = {cw01[j], cw01[j]};
                const f32x2 W10 = {cw10[j], cw10[j]}, W11 = {cw11[j], cw11[j]};
                S8I res;
                #pragma unroll
                for (int pc = 0; pc < 4; ++pc) {
                    const int e00 = u00[j].i[pc], e01 = u01[j].i[pc];
                    const int e10 = u10[j].i[pc], e11 = u11[j].i[pc];
                    f32x2 a00 = {bflo(e00), bfhi(e00)};
                    f32x2 a01 = {bflo(e01), bfhi(e01)};
                    f32x2 a10 = {bflo(e10), bfhi(e10)};
                    f32x2 a11 = {bflo(e11), bfhi(e11)};
                    f32x2 v = a00 * W00;
                    v += a01 * W01;
                    v += a10 * W10;
                    v += a11 * W11;
                    res.i[pc] = (int)__builtin_amdgcn_perm(rnd2(v.y), rnd2(v.x), 0x07060302u);
                }

                // res.s IS the B-fragment for chunk (h,i); afr via lgkmcnt
                #pragma unroll
                for (int ot = 0; ot < 4; ++ot) {
                    const short8 afr = *(const short8*)&s_wf[(i * 4 + ot) * 512 + lane * 8];
                    acc[ot] = __builtin_amdgcn_mfma_f32_16x16x32_bf16(afr, res.s, acc[ot], 0, 0, 0);
                }
            }
        }
    }

    // ---- epilogue: o = ot*16 + q4*4 + r ----
    #pragma unroll
    for (int ot = 0; ot < 4; ++ot)
        #pragma unroll
        for (int r = 0; r < 4; ++r)
            out[((b * CO + ot * 16 + q4 * 4 + r) * HH + ho) * WW + px] = acc[ot][r];
}

extern "C" void kernel_launch(void* const* d_in, const int* in_sizes, int n_in,
                              void* d_out, int out_size, void* d_ws, size_t ws_size,
                              hipStream_t stream) {
    const float* in   = (const float*)d_in[0];
    const float* off  = (const float*)d_in[1];
    const float* msk  = (const float*)d_in[2];
    const float* wt   = (const float*)d_in[3];
    const float* bias = (const float*)d_in[4];
    float* out = (float*)d_out;
    short* wf   = (short*)d_ws;            // 36864 shorts = 72 KB
    short* in_t = (short*)d_ws + 36864;    // 4*8*16384*8 shorts = 8 MB

    prep<<<144 + 2048, 256, 0, stream>>>(wt, in, wf, in_t);

    dcn_fused<<<1024, 256, 0, stream>>>(in_t, off, msk, wf, bias, out);
}